// Round 2
// baseline (858.289 us; speedup 1.0000x reference)
//
#include <hip/hip_runtime.h>
#include <math.h>

#define BB 2
#define NN 2048
#define DD 512
#define HH 8
#define DHH 64
#define FF 2048
#define MROWS (BB*NN)   // 4096
#define LN_EPS 1e-5f
#define PHASE_ALPHA 0.1f
#define PI_F 3.14159265358979323846f
#define SCALE 0.125f    // 1/sqrt(64)

// ---------------------------------------------------------------- GEMM
// C[M,Nc] = A[M,K] @ W[K,Nc] (+bias) (+gelu).
// Tile 128(M) x 64(N), BK=16, 256 threads, 8x4 per thread.
// Register-staged prefetch: next k-tile's global loads issue before compute.
template<int BIAS, int ACT>
__global__ __launch_bounds__(256) void gemm_kernel(
    const float* __restrict__ A, const float* __restrict__ W,
    const float* __restrict__ bias, float* __restrict__ C,
    int M, int Nc, int K)
{
    __shared__ float As[16][132];  // [k][m] transposed, pad 132 (4k+m banks: 2-way, free)
    __shared__ float Bs[16][68];   // [k][n]

    const int tid = threadIdx.x;
    const int tx = tid & 15;       // col group -> 4 cols
    const int ty = tid >> 4;       // row group -> 8 rows
    const int bm = blockIdx.y * 128, bn = blockIdx.x * 64;

    const int ra = tid & 127;      // A row within tile
    const int qa = tid >> 7;       // k-half (0/1) -> k offset 8*qa
    const int kb = tid >> 4;       // B k-row (0-15)
    const int cb = (tid & 15) * 4; // B col

    const float* Aptr = A + (size_t)(bm + ra)*K + qa*8;
    const float* Wptr = W + (size_t)kb*Nc + bn + cb;

    // prefetch tile 0
    float4 a0 = *(const float4*)(Aptr);
    float4 a1 = *(const float4*)(Aptr + 4);
    float4 b0 = *(const float4*)(Wptr);

    float acc[8][4] = {};
    const int NT = K / 16;

    for (int t = 0; t < NT; ++t) {
        __syncthreads();   // previous compute done before LDS overwrite
        {
            const int ka = qa*8;
            As[ka+0][ra] = a0.x; As[ka+1][ra] = a0.y;
            As[ka+2][ra] = a0.z; As[ka+3][ra] = a0.w;
            As[ka+4][ra] = a1.x; As[ka+5][ra] = a1.y;
            As[ka+6][ra] = a1.z; As[ka+7][ra] = a1.w;
            *(float4*)&Bs[kb][cb] = b0;
        }
        __syncthreads();   // LDS visible
        if (t + 1 < NT) {  // issue next tile's loads; latency hides under compute
            a0 = *(const float4*)(Aptr + (size_t)(t+1)*16);
            a1 = *(const float4*)(Aptr + (size_t)(t+1)*16 + 4);
            b0 = *(const float4*)(Wptr + (size_t)(t+1)*16*Nc);
        }
        #pragma unroll
        for (int kk = 0; kk < 16; ++kk) {
            float4 av0 = *(const float4*)&As[kk][ty*8];
            float4 av1 = *(const float4*)&As[kk][ty*8 + 4];
            float4 bv  = *(const float4*)&Bs[kk][tx*4];
            float aa[8] = {av0.x,av0.y,av0.z,av0.w,av1.x,av1.y,av1.z,av1.w};
            float bb[4] = {bv.x,bv.y,bv.z,bv.w};
            #pragma unroll
            for (int i = 0; i < 8; ++i)
                #pragma unroll
                for (int j = 0; j < 4; ++j)
                    acc[i][j] += aa[i] * bb[j];
        }
    }

    #pragma unroll
    for (int i = 0; i < 8; ++i) {
        int row = bm + ty*8 + i;
        float v[4];
        #pragma unroll
        for (int j = 0; j < 4; ++j) {
            float x = acc[i][j];
            if (BIAS) x += bias[bn + tx*4 + j];
            if (ACT == 1) x = 0.5f * x * (1.f + erff(x * 0.70710678118654752f));
            v[j] = x;
        }
        float4 o; o.x = v[0]; o.y = v[1]; o.z = v[2]; o.w = v[3];
        *(float4*)&C[(size_t)row*Nc + bn + tx*4] = o;
    }
}

// ------------------------------------------------- phase projection + cos/sin
__global__ __launch_bounds__(256) void phase_proj_kernel(
    const float* __restrict__ X, const float* __restrict__ Wp,
    const float* __restrict__ bp, float* __restrict__ cosP, float* __restrict__ sinP)
{
    __shared__ float Wl[DD*HH];
    for (int i = threadIdx.x; i < DD*HH; i += 256) Wl[i] = Wp[i];
    __syncthreads();
    int row = blockIdx.x*32 + (threadIdx.x >> 3);
    int hh  = threadIdx.x & 7;
    const float* xr = X + (size_t)row * DD;
    float acc = bp[hh];
    for (int k = 0; k < DD; k += 4) {
        float4 xv = *(const float4*)&xr[k];
        acc += xv.x*Wl[(k  )*HH+hh] + xv.y*Wl[(k+1)*HH+hh]
             + xv.z*Wl[(k+2)*HH+hh] + xv.w*Wl[(k+3)*HH+hh];
    }
    cosP[row*HH + hh] = cosf(acc);
    sinP[row*HH + hh] = sinf(acc);
}

// ------------------------------------------------- final phase update
__global__ __launch_bounds__(256) void phase_update_kernel(
    const float* __restrict__ H2, const float* __restrict__ Wph,
    const float* __restrict__ bph, const float* __restrict__ phases,
    float* __restrict__ phases_out)
{
    __shared__ float Wl[DD*HH];
    for (int i = threadIdx.x; i < DD*HH; i += 256) Wl[i] = Wph[i];
    __syncthreads();
    int row = blockIdx.x*32 + (threadIdx.x >> 3);
    int hh  = threadIdx.x & 7;
    const float* xr = H2 + (size_t)row * DD;
    float acc = bph[hh];
    for (int k = 0; k < DD; k += 4) {
        float4 xv = *(const float4*)&xr[k];
        acc += xv.x*Wl[(k  )*HH+hh] + xv.y*Wl[(k+1)*HH+hh]
             + xv.z*Wl[(k+2)*HH+hh] + xv.w*Wl[(k+3)*HH+hh];
    }
    phases_out[row*HH + hh] = phases[row*HH + hh] + PHASE_ALPHA * tanhf(acc) * PI_F;
}

// ------------------------------------------------- flash attention w/ harmonic
// 64-row Q tile per block, online softmax; harmonic cos(a-b) separated into
// cos*cos + sin*sin so it's applied per 64x64 S-tile in registers.
__global__ __launch_bounds__(256) void attn_kernel(
    const float* __restrict__ Qg, const float* __restrict__ Kg, const float* __restrict__ Vg,
    const float* __restrict__ cosP, const float* __restrict__ sinP,
    const unsigned char* __restrict__ mask, float* __restrict__ msg)
{
    __shared__ float Qs[DHH][68];  // [d][r] transposed Q tile
    __shared__ float KP[DHH][68];  // [d][m] K tile, reused as [r][m] P tile
    __shared__ float Vs[64][DHH];  // [m][d]

    const int tid = threadIdx.x;
    const int tx = tid & 15, ty = tid >> 4;
    const int qBase = blockIdx.x * 64;
    const int hh = blockIdx.y;
    const int b  = blockIdx.z;
    const size_t rowOff = (size_t)b * NN;

    const float* Qb = Qg + rowOff*DD + hh*DHH;
    const float* Kb = Kg + rowOff*DD + hh*DHH;
    const float* Vb = Vg + rowOff*DD + hh*DHH;

    const int ld  = tid & 63;  // d (or col)
    const int lr0 = tid >> 6;  // 0..3

    #pragma unroll
    for (int i = 0; i < 16; ++i) {
        int r = lr0 + i*4;
        Qs[ld][r] = Qb[(size_t)(qBase + r)*DD + ld];
    }

    float cq[4], sq_[4];
    #pragma unroll
    for (int i = 0; i < 4; ++i) {
        int r = qBase + ty*4 + i;
        cq[i]  = cosP[(rowOff + r)*HH + hh];
        sq_[i] = sinP[(rowOff + r)*HH + hh];
    }

    float acc[4][4] = {};
    float mrow[4], lrow[4];
    #pragma unroll
    for (int i = 0; i < 4; ++i) { mrow[i] = -INFINITY; lrow[i] = 0.f; }

    for (int mt = 0; mt < NN/64; ++mt) {
        const int mBase = mt * 64;
        #pragma unroll
        for (int i = 0; i < 16; ++i) {
            int m = lr0 + i*4;
            KP[ld][m]  = Kb[(size_t)(mBase + m)*DD + ld];
            Vs[m][ld]  = Vb[(size_t)(mBase + m)*DD + ld];
        }
        float ck[4], sk[4];
        unsigned char mk[4];
        #pragma unroll
        for (int j = 0; j < 4; ++j) {
            int m = mBase + tx*4 + j;
            ck[j] = cosP[(rowOff + m)*HH + hh];
            sk[j] = sinP[(rowOff + m)*HH + hh];
            mk[j] = mask[rowOff + m];
        }
        __syncthreads();

        // S = (Q K^T) * SCALE * 0.5*(1 + cq*ck + sq*sk), then mask
        float s[4][4] = {};
        #pragma unroll 8
        for (int d = 0; d < DHH; ++d) {
            float4 qv = *(const float4*)&Qs[d][ty*4];
            float4 kv = *(const float4*)&KP[d][tx*4];
            float a_[4] = {qv.x, qv.y, qv.z, qv.w};
            float b_[4] = {kv.x, kv.y, kv.z, kv.w};
            #pragma unroll
            for (int i = 0; i < 4; ++i)
                #pragma unroll
                for (int j = 0; j < 4; ++j)
                    s[i][j] += a_[i] * b_[j];
        }
        #pragma unroll
        for (int i = 0; i < 4; ++i)
            #pragma unroll
            for (int j = 0; j < 4; ++j) {
                float w = 0.5f * (1.f + cq[i]*ck[j] + sq_[i]*sk[j]);
                float v = s[i][j] * SCALE * w;
                s[i][j] = mk[j] ? -INFINITY : v;
            }

        // row max across the 16 tx threads sharing each row
        float tmax[4];
        #pragma unroll
        for (int i = 0; i < 4; ++i) {
            float m4 = fmaxf(fmaxf(s[i][0], s[i][1]), fmaxf(s[i][2], s[i][3]));
            #pragma unroll
            for (int msk = 1; msk < 16; msk <<= 1)
                m4 = fmaxf(m4, __shfl_xor(m4, msk, 16));
            tmax[i] = m4;
        }

        __syncthreads();   // everyone done reading KP (K) before P overwrite

        #pragma unroll
        for (int i = 0; i < 4; ++i) {
            float mnew = fmaxf(mrow[i], tmax[i]);
            float corr = (mrow[i] == -INFINITY) ? 0.f : __expf(mrow[i] - mnew);
            float psum = 0.f;
            #pragma unroll
            for (int j = 0; j < 4; ++j) {
                float p = (s[i][j] == -INFINITY) ? 0.f : __expf(s[i][j] - mnew);
                KP[ty*4 + i][tx*4 + j] = p;
                psum += p;
            }
            #pragma unroll
            for (int msk = 1; msk < 16; msk <<= 1)
                psum += __shfl_xor(psum, msk, 16);
            lrow[i] = lrow[i]*corr + psum;
            mrow[i] = mnew;
            #pragma unroll
            for (int j = 0; j < 4; ++j) acc[i][j] *= corr;
        }
        __syncthreads();   // P visible

        // acc += P @ V   (P read as float4 per 4-m group: fewer LDS cycles)
        #pragma unroll
        for (int m0 = 0; m0 < 64; m0 += 4) {
            float4 pr[4];
            #pragma unroll
            for (int i = 0; i < 4; ++i)
                pr[i] = *(const float4*)&KP[ty*4 + i][m0];
            #pragma unroll
            for (int k2 = 0; k2 < 4; ++k2) {
                float4 vv = *(const float4*)&Vs[m0 + k2][tx*4];
                float vb[4] = {vv.x, vv.y, vv.z, vv.w};
                #pragma unroll
                for (int i = 0; i < 4; ++i) {
                    float pk = ((const float*)&pr[i])[k2];
                    #pragma unroll
                    for (int j = 0; j < 4; ++j)
                        acc[i][j] += pk * vb[j];
                }
            }
        }
        __syncthreads();   // before next tile overwrites KP/Vs
    }

    #pragma unroll
    for (int i = 0; i < 4; ++i) {
        float inv = 1.f / lrow[i];
        int r = qBase + ty*4 + i;
        float4 o;
        o.x = acc[i][0]*inv; o.y = acc[i][1]*inv;
        o.z = acc[i][2]*inv; o.w = acc[i][3]*inv;
        *(float4*)&msg[(rowOff + r)*DD + hh*DHH + tx*4] = o;
    }
}

// ------------------------------------------------- residual + LayerNorm (+delta)
template<int WITH_DELTA>
__global__ __launch_bounds__(256) void ln_kernel(
    const float* __restrict__ x, const float* __restrict__ y,
    const float* __restrict__ g, const float* __restrict__ bvec,
    float* __restrict__ out, const float* __restrict__ href, float* __restrict__ deltaAcc)
{
    const int row = blockIdx.x;
    const int tid = threadIdx.x;
    const size_t base = (size_t)row * DD + tid*2;
    float2 xv = *(const float2*)(x + base);
    float2 yv = *(const float2*)(y + base);
    float v0 = xv.x + yv.x;
    float v1 = xv.y + yv.y;
    float s  = v0 + v1;
    float sq = v0*v0 + v1*v1;
    #pragma unroll
    for (int m = 1; m < 64; m <<= 1) {
        s  += __shfl_xor(s,  m, 64);
        sq += __shfl_xor(sq, m, 64);
    }
    __shared__ float redS[4], redQ[4];
    int wv = tid >> 6;
    if ((tid & 63) == 0) { redS[wv] = s; redQ[wv] = sq; }
    __syncthreads();
    s  = redS[0] + redS[1] + redS[2] + redS[3];
    sq = redQ[0] + redQ[1] + redQ[2] + redQ[3];
    float mu  = s * (1.f/DD);
    float var = sq * (1.f/DD) - mu*mu;
    float inv = rsqrtf(var + LN_EPS);
    float o0 = (v0 - mu)*inv*g[tid*2  ] + bvec[tid*2  ];
    float o1 = (v1 - mu)*inv*g[tid*2+1] + bvec[tid*2+1];
    float2 ov; ov.x = o0; ov.y = o1;
    *(float2*)(out + base) = ov;

    if (WITH_DELTA) {
        float2 hv = *(const float2*)(href + base);
        float d0 = o0 - hv.x, d1 = o1 - hv.y;
        float ds = d0*d0 + d1*d1;
        #pragma unroll
        for (int m = 1; m < 64; m <<= 1) ds += __shfl_xor(ds, m, 64);
        __shared__ float redD[4];
        if ((tid & 63) == 0) redD[wv] = ds;
        __syncthreads();
        if (tid == 0) {
            float t = redD[0] + redD[1] + redD[2] + redD[3];
            atomicAdd(deltaAcc, sqrtf(t));
        }
    }
}

__global__ void delta_finalize(const float* __restrict__ acc, float* __restrict__ out)
{
    out[0] = acc[0] * (1.f / (float)MROWS);
}

// ---------------------------------------------------------------- launch
extern "C" void kernel_launch(void* const* d_in, const int* in_sizes, int n_in,
                              void* d_out, int out_size, void* d_ws, size_t ws_size,
                              hipStream_t stream)
{
    (void)in_sizes; (void)n_in; (void)out_size; (void)ws_size;
    const float* h      = (const float*)d_in[0];
    const float* phases = (const float*)d_in[1];
    const unsigned char* mask = (const unsigned char*)d_in[2];
    const float* Wq  = (const float*)d_in[3];
    const float* Wk  = (const float*)d_in[4];
    const float* Wp  = (const float*)d_in[5];
    const float* bp  = (const float*)d_in[6];
    const float* Wv  = (const float*)d_in[7];
    const float* Wo  = (const float*)d_in[8];
    const float* W1  = (const float*)d_in[9];
    const float* b1  = (const float*)d_in[10];
    const float* W2  = (const float*)d_in[11];
    const float* b2  = (const float*)d_in[12];
    const float* g1  = (const float*)d_in[13];
    const float* be1 = (const float*)d_in[14];
    const float* g2  = (const float*)d_in[15];
    const float* be2 = (const float*)d_in[16];
    const float* Wph = (const float*)d_in[17];
    const float* bph = (const float*)d_in[18];

    float* ws   = (float*)d_ws;
    float* Q    = ws;
    float* K    = Q   + (size_t)MROWS*DD;
    float* V    = K   + (size_t)MROWS*DD;
    float* msg  = V   + (size_t)MROWS*DD;
    float* h1   = msg + (size_t)MROWS*DD;
    float* T1   = h1  + (size_t)MROWS*DD;
    float* cosP = T1  + (size_t)MROWS*FF;
    float* sinP = cosP + MROWS*HH;
    float* dAcc = sinP + MROWS*HH;
    float* mo   = Q;   // alias: Q dead after attn
    float* ffnb = K;   // alias: K dead after attn

    float* out_h2    = (float*)d_out;
    float* out_ph    = out_h2 + (size_t)MROWS*DD;
    float* out_delta = out_ph + MROWS*HH;

    hipMemsetAsync(dAcc, 0, sizeof(float), stream);

    dim3 blk(256);
    dim3 gD(DD/64, MROWS/128);    // 8 x 32 = 256 blocks (1/CU)
    dim3 gF(FF/64, MROWS/128);    // 32 x 32 = 1024 blocks
    gemm_kernel<0,0><<<gD, blk, 0, stream>>>(h,   Wq, nullptr, Q,  MROWS, DD, DD);
    gemm_kernel<0,0><<<gD, blk, 0, stream>>>(h,   Wk, nullptr, K,  MROWS, DD, DD);
    gemm_kernel<0,0><<<gD, blk, 0, stream>>>(h,   Wv, nullptr, V,  MROWS, DD, DD);
    phase_proj_kernel<<<dim3(MROWS/32), blk, 0, stream>>>(h, Wp, bp, cosP, sinP);
    attn_kernel<<<dim3(NN/64, HH, BB), blk, 0, stream>>>(Q, K, V, cosP, sinP, mask, msg);
    gemm_kernel<0,0><<<gD, blk, 0, stream>>>(msg, Wo, nullptr, mo, MROWS, DD, DD);
    ln_kernel<0><<<dim3(MROWS), blk, 0, stream>>>(h, mo, g1, be1, h1, nullptr, nullptr);
    gemm_kernel<1,1><<<gF, blk, 0, stream>>>(h1, W1, b1, T1, MROWS, FF, DD);
    gemm_kernel<1,0><<<gD, blk, 0, stream>>>(T1, W2, b2, ffnb, MROWS, DD, FF);
    ln_kernel<1><<<dim3(MROWS), blk, 0, stream>>>(h1, ffnb, g2, be2, out_h2, h, dAcc);
    phase_update_kernel<<<dim3(MROWS/32), blk, 0, stream>>>(out_h2, Wph, bph, phases, out_ph);
    delta_finalize<<<dim3(1), dim3(1), 0, stream>>>(dAcc, out_delta);
}

// Round 5
// 614.420 us; speedup vs baseline: 1.3969x; 1.3969x over previous
//
#include <hip/hip_runtime.h>
#include <math.h>

#define BB 2
#define NN 2048
#define DD 512
#define HH 8
#define DHH 64
#define FF 2048
#define MROWS (BB*NN)   // 4096
#define LN_EPS 1e-5f
#define PHASE_ALPHA 0.1f
#define PI_F 3.14159265358979323846f
#define SCALE 0.125f    // 1/sqrt(64)

typedef __attribute__((ext_vector_type(8))) short  bf16x8;
typedef __attribute__((ext_vector_type(4))) float  f32x4;
typedef __attribute__((ext_vector_type(4))) unsigned short us4;

__device__ __forceinline__ unsigned short f2bf(float x) {
    unsigned int u = __float_as_uint(x);
    u += 0x7fffu + ((u >> 16) & 1u);      // RNE
    return (unsigned short)(u >> 16);
}

// ---------------------------------------------------------------- bf16 convert
__global__ __launch_bounds__(256) void convert_bf16_kernel(
    const float* __restrict__ X, unsigned short* __restrict__ Y, int n8)
{
    int i = blockIdx.x*256 + threadIdx.x;
    if (i >= n8) return;
    const float4 a = *(const float4*)&X[i*8];
    const float4 b = *(const float4*)&X[i*8 + 4];
    uint4 o;
    o.x = (unsigned)f2bf(a.x) | ((unsigned)f2bf(a.y) << 16);
    o.y = (unsigned)f2bf(a.z) | ((unsigned)f2bf(a.w) << 16);
    o.z = (unsigned)f2bf(b.x) | ((unsigned)f2bf(b.y) << 16);
    o.w = (unsigned)f2bf(b.z) | ((unsigned)f2bf(b.w) << 16);
    *(uint4*)&Y[i*8] = o;
}

// ------------------------------------------- weight transpose f32[K][N] -> bf16[N][K]
__global__ __launch_bounds__(256) void wtrans_kernel(
    const float* __restrict__ W, unsigned short* __restrict__ WT, int K, int N)
{
    __shared__ unsigned short T[32][33];
    const int k0 = blockIdx.y*32, n0 = blockIdx.x*32;
    const int r = threadIdx.x >> 3, cc = (threadIdx.x & 7)*4;
    float4 v = *(const float4*)&W[(size_t)(k0 + r)*N + n0 + cc];
    T[cc+0][r] = f2bf(v.x); T[cc+1][r] = f2bf(v.y);
    T[cc+2][r] = f2bf(v.z); T[cc+3][r] = f2bf(v.w);
    __syncthreads();
    us4 o; o.x = T[r][cc]; o.y = T[r][cc+1]; o.z = T[r][cc+2]; o.w = T[r][cc+3];
    *(us4*)&WT[(size_t)(n0 + r)*K + k0 + cc] = o;
}

// ------------------------------------------- V transpose bf16[b*N][D] -> VT[(b,h,dh)][N]
__global__ __launch_bounds__(256) void vtrans_kernel(
    const unsigned short* __restrict__ Vb, unsigned short* __restrict__ VT)
{
    __shared__ unsigned short T[32][33];
    const int b = blockIdx.z;
    const int n0 = blockIdx.x*32, c0 = blockIdx.y*32;
    const int r = threadIdx.x >> 3, cc = (threadIdx.x & 7)*4;
    us4 v = *(const us4*)&Vb[((size_t)b*NN + n0 + r)*DD + c0 + cc];
    T[cc+0][r] = v.x; T[cc+1][r] = v.y; T[cc+2][r] = v.z; T[cc+3][r] = v.w;
    __syncthreads();
    const int cg = c0 + r;                 // global col = h*64+dh
    const int hh = cg >> 6, dh = cg & 63;
    us4 o; o.x = T[r][cc]; o.y = T[r][cc+1]; o.z = T[r][cc+2]; o.w = T[r][cc+3];
    *(us4*)&VT[(((size_t)b*HH + hh)*DHH + dh)*NN + n0 + cc] = o;
}

// ---------------------------------------------------------------- MFMA GEMM
// C[M,Nc] = A[M,K] @ BT[Nc,K]^T, A/BT bf16 row-major K-contiguous.
// 128x128 tile, BK=64, 4 waves (2x2), each wave 64x64 = 4x4 frags of 16x16x32.
template<int OUTBF16, int BIAS, int ACT>
__global__ __launch_bounds__(256, 2) void mfma_gemm(
    const unsigned short* __restrict__ A, const unsigned short* __restrict__ BT,
    const float* __restrict__ bias, void* __restrict__ Cout,
    int M, int Nc, int K)
{
    __shared__ unsigned short As[128][72];   // rows 144B: 2-way conflicts only
    __shared__ unsigned short Bs[128][72];

    const int tid = threadIdx.x;
    const int w = tid >> 6, lane = tid & 63;
    const int c = lane & 15, g = lane >> 4;
    const int wr = w >> 1, wc = w & 1;
    const int bm = blockIdx.y*128, bn = blockIdx.x*128;
    const int lrow = tid >> 3, lkc = (tid & 7)*8;

    const int NT = K / 64;
    f32x4 zero = {0.f, 0.f, 0.f, 0.f};
    f32x4 acc[4][4];
    #pragma unroll
    for (int i = 0; i < 4; ++i)
        #pragma unroll
        for (int j = 0; j < 4; ++j) acc[i][j] = zero;

    uint4 pa[4], pb[4];
    #pragma unroll
    for (int p = 0; p < 4; ++p) {
        pa[p] = *(const uint4*)&A [(size_t)(bm + lrow + p*32)*K + lkc];
        pb[p] = *(const uint4*)&BT[(size_t)(bn + lrow + p*32)*K + lkc];
    }

    for (int kt = 0; kt < NT; ++kt) {
        __syncthreads();
        #pragma unroll
        for (int p = 0; p < 4; ++p) {
            *(uint4*)&As[lrow + p*32][lkc] = pa[p];
            *(uint4*)&Bs[lrow + p*32][lkc] = pb[p];
        }
        __syncthreads();
        if (kt + 1 < NT) {
            #pragma unroll
            for (int p = 0; p < 4; ++p) {
                pa[p] = *(const uint4*)&A [(size_t)(bm + lrow + p*32)*K + (kt+1)*64 + lkc];
                pb[p] = *(const uint4*)&BT[(size_t)(bn + lrow + p*32)*K + (kt+1)*64 + lkc];
            }
        }
        #pragma unroll
        for (int ks = 0; ks < 2; ++ks) {
            bf16x8 af[4], bf[4];
            #pragma unroll
            for (int mf = 0; mf < 4; ++mf)
                af[mf] = *(const bf16x8*)&As[wr*64 + mf*16 + c][ks*32 + g*8];
            #pragma unroll
            for (int nf = 0; nf < 4; ++nf)
                bf[nf] = *(const bf16x8*)&Bs[wc*64 + nf*16 + c][ks*32 + g*8];
            #pragma unroll
            for (int mf = 0; mf < 4; ++mf)
                #pragma unroll
                for (int nf = 0; nf < 4; ++nf)
                    acc[mf][nf] = __builtin_amdgcn_mfma_f32_16x16x32_bf16(
                        af[mf], bf[nf], acc[mf][nf], 0, 0, 0);
        }
    }

    #pragma unroll
    for (int mf = 0; mf < 4; ++mf)
        #pragma unroll
        for (int nf = 0; nf < 4; ++nf) {
            const int col = bn + wc*64 + nf*16 + c;
            const float bv = BIAS ? bias[col] : 0.f;
            #pragma unroll
            for (int r = 0; r < 4; ++r) {
                const int row = bm + wr*64 + mf*16 + g*4 + r;
                float x = acc[mf][nf][r] + bv;
                if (ACT == 1) x = 0.5f * x * (1.f + erff(x * 0.70710678118654752f));
                if (OUTBF16) ((unsigned short*)Cout)[(size_t)row*Nc + col] = f2bf(x);
                else         ((float*)Cout)[(size_t)row*Nc + col] = x;
            }
        }
}

// ------------------------------------------------- phase projection + cos/sin (-> [b,h][n])
__global__ __launch_bounds__(256) void phase_proj_kernel(
    const float* __restrict__ X, const float* __restrict__ Wp,
    const float* __restrict__ bp, float* __restrict__ cosPt, float* __restrict__ sinPt)
{
    __shared__ float Wl[DD*HH];
    for (int i = threadIdx.x; i < DD*HH; i += 256) Wl[i] = Wp[i];
    __syncthreads();
    int row = blockIdx.x*32 + (threadIdx.x >> 3);
    int hh  = threadIdx.x & 7;
    const float* xr = X + (size_t)row * DD;
    float acc = bp[hh];
    for (int k = 0; k < DD; k += 4) {
        float4 xv = *(const float4*)&xr[k];
        acc += xv.x*Wl[(k  )*HH+hh] + xv.y*Wl[(k+1)*HH+hh]
             + xv.z*Wl[(k+2)*HH+hh] + xv.w*Wl[(k+3)*HH+hh];
    }
    const int b = row >> 11, n = row & (NN-1);
    cosPt[((size_t)b*HH + hh)*NN + n] = cosf(acc);
    sinPt[((size_t)b*HH + hh)*NN + n] = sinf(acc);
}

// ------------------------------------------------- final phase update
__global__ __launch_bounds__(256) void phase_update_kernel(
    const float* __restrict__ H2, const float* __restrict__ Wph,
    const float* __restrict__ bph, const float* __restrict__ phases,
    float* __restrict__ phases_out)
{
    __shared__ float Wl[DD*HH];
    for (int i = threadIdx.x; i < DD*HH; i += 256) Wl[i] = Wph[i];
    __syncthreads();
    int row = blockIdx.x*32 + (threadIdx.x >> 3);
    int hh  = threadIdx.x & 7;
    const float* xr = H2 + (size_t)row * DD;
    float acc = bph[hh];
    for (int k = 0; k < DD; k += 4) {
        float4 xv = *(const float4*)&xr[k];
        acc += xv.x*Wl[(k  )*HH+hh] + xv.y*Wl[(k+1)*HH+hh]
             + xv.z*Wl[(k+2)*HH+hh] + xv.w*Wl[(k+3)*HH+hh];
    }
    phases_out[row*HH + hh] = phases[row*HH + hh] + PHASE_ALPHA * tanhf(acc) * PI_F;
}

// ------------------------------------------------- MFMA flash attention w/ harmonic
// Per block: (b, h, 64-q tile). 4 waves; wave w owns 32-key subtiles s%4==w
// (independent online softmax; merged at end). S^T = K·Q^T via MFMA so the
// key-reduction is in-lane + shfl(16,32). PV as O^T = V^T·P^T (VT pre-transposed).
__global__ __launch_bounds__(256, 2) void attn_kernel(
    const unsigned short* __restrict__ Qb, const unsigned short* __restrict__ Kb,
    const unsigned short* __restrict__ VT,
    const float* __restrict__ cosPt, const float* __restrict__ sinPt,
    const unsigned char* __restrict__ mask, unsigned short* __restrict__ msgb)
{
    __shared__ float Os[64][68];          // O^T accum [dh][q]
    __shared__ float MwS[4][64], LwS[4][64];
    __shared__ unsigned short Pl[4][64][40];   // per-wave P [q][key_rel], 80B rows

    const int tid = threadIdx.x;
    const int w = tid >> 6, lane = tid & 63;
    const int c = lane & 15, g = lane >> 4;
    const int qBase = blockIdx.x * 64;
    const int hh = blockIdx.y, b = blockIdx.z;
    const size_t rowOff = (size_t)b * NN;
    const int bh = b*HH + hh;
    const size_t cosBase = (size_t)bh * NN;

    for (int i = tid; i < 64*68; i += 256) ((float*)Os)[i] = 0.f;

    // Q B-frags (held in registers for the whole block)
    bf16x8 qf[4][2];
    #pragma unroll
    for (int nf = 0; nf < 4; ++nf)
        #pragma unroll
        for (int ks = 0; ks < 2; ++ks)
            qf[nf][ks] = *(const bf16x8*)&Qb[(rowOff + qBase + nf*16 + c)*DD
                                             + hh*DHH + ks*32 + g*8];
    float cq[4], sq[4];
    #pragma unroll
    for (int nf = 0; nf < 4; ++nf) {
        cq[nf] = cosPt[cosBase + qBase + nf*16 + c];
        sq[nf] = sinPt[cosBase + qBase + nf*16 + c];
    }

    f32x4 zero = {0.f, 0.f, 0.f, 0.f};
    f32x4 acc[4][4];
    #pragma unroll
    for (int i = 0; i < 4; ++i)
        #pragma unroll
        for (int j = 0; j < 4; ++j) acc[i][j] = zero;
    float mst[4], lst[4];
    #pragma unroll
    for (int i = 0; i < 4; ++i) { mst[i] = -INFINITY; lst[i] = 0.f; }

    __syncthreads();   // Os zeroed

    for (int s = w; s < NN/32; s += 4) {
        const int kb0 = s * 32;
        // ---- S^T = K·Q^T (32 keys x 64 q)
        f32x4 st[2][4];
        #pragma unroll
        for (int mf = 0; mf < 2; ++mf) {
            bf16x8 kf0 = *(const bf16x8*)&Kb[(rowOff + kb0 + mf*16 + c)*DD + hh*DHH + g*8];
            bf16x8 kf1 = *(const bf16x8*)&Kb[(rowOff + kb0 + mf*16 + c)*DD + hh*DHH + 32 + g*8];
            #pragma unroll
            for (int nf = 0; nf < 4; ++nf) {
                st[mf][nf] = __builtin_amdgcn_mfma_f32_16x16x32_bf16(kf0, qf[nf][0], zero, 0, 0, 0);
                st[mf][nf] = __builtin_amdgcn_mfma_f32_16x16x32_bf16(kf1, qf[nf][1], st[mf][nf], 0, 0, 0);
            }
        }
        // ---- harmonic * scale, mask
        #pragma unroll
        for (int mf = 0; mf < 2; ++mf) {
            const int keyb = kb0 + mf*16 + g*4;
            const f32x4 ck = *(const f32x4*)&cosPt[cosBase + keyb];
            const f32x4 sk = *(const f32x4*)&sinPt[cosBase + keyb];
            const unsigned int mk = *(const unsigned int*)&mask[rowOff + keyb];
            #pragma unroll
            for (int nf = 0; nf < 4; ++nf)
                #pragma unroll
                for (int r = 0; r < 4; ++r) {
                    float wgt = 0.5f + 0.5f*(cq[nf]*ck[r] + sq[nf]*sk[r]);
                    float v = st[mf][nf][r] * SCALE * wgt;
                    st[mf][nf][r] = ((mk >> (8*r)) & 0xff) ? -INFINITY : v;
                }
        }
        // ---- online softmax per q-column (keys: in-lane mf,r + lanes g)
        #pragma unroll
        for (int nf = 0; nf < 4; ++nf) {
            float tmax = -INFINITY;
            #pragma unroll
            for (int mf = 0; mf < 2; ++mf)
                #pragma unroll
                for (int r = 0; r < 4; ++r) tmax = fmaxf(tmax, st[mf][nf][r]);
            tmax = fmaxf(tmax, __shfl_xor(tmax, 16));
            tmax = fmaxf(tmax, __shfl_xor(tmax, 32));
            const float mnew = fmaxf(mst[nf], tmax);
            const float corr = (mst[nf] == -INFINITY) ? 0.f : __expf(mst[nf] - mnew);
            float psum = 0.f;
            unsigned short* prow = &Pl[w][nf*16 + c][0];
            #pragma unroll
            for (int mf = 0; mf < 2; ++mf) {
                float p0 = __expf(st[mf][nf][0] - mnew);
                float p1 = __expf(st[mf][nf][1] - mnew);
                float p2 = __expf(st[mf][nf][2] - mnew);
                float p3 = __expf(st[mf][nf][3] - mnew);
                psum += (p0 + p1) + (p2 + p3);
                *(unsigned int*)&prow[mf*16 + g*4    ] = (unsigned)f2bf(p0) | ((unsigned)f2bf(p1) << 16);
                *(unsigned int*)&prow[mf*16 + g*4 + 2] = (unsigned)f2bf(p2) | ((unsigned)f2bf(p3) << 16);
            }
            psum += __shfl_xor(psum, 16);
            psum += __shfl_xor(psum, 32);
            lst[nf] = lst[nf]*corr + psum;
            mst[nf] = mnew;
            #pragma unroll
            for (int mo = 0; mo < 4; ++mo)
                #pragma unroll
                for (int r = 0; r < 4; ++r) acc[mo][nf][r] *= corr;
        }
        // ---- O^T += V^T · P^T  (wave-private, no barrier needed)
        bf16x8 vf[4], pf[4];
        #pragma unroll
        for (int mo = 0; mo < 4; ++mo)
            vf[mo] = *(const bf16x8*)&VT[((size_t)bh*DHH + mo*16 + c)*NN + kb0 + g*8];
        #pragma unroll
        for (int nf = 0; nf < 4; ++nf)
            pf[nf] = *(const bf16x8*)&Pl[w][nf*16 + c][g*8];
        #pragma unroll
        for (int mo = 0; mo < 4; ++mo)
            #pragma unroll
            for (int nf = 0; nf < 4; ++nf)
                acc[mo][nf] = __builtin_amdgcn_mfma_f32_16x16x32_bf16(
                    vf[mo], pf[nf], acc[mo][nf], 0, 0, 0);
    }

    // ---- merge the 4 wave-partials
    if (lane < 16) {
        #pragma unroll
        for (int nf = 0; nf < 4; ++nf) {
            MwS[w][nf*16 + lane] = mst[nf];
            LwS[w][nf*16 + lane] = lst[nf];
        }
    }
    __syncthreads();
    float fac[4];
    #pragma unroll
    for (int nf = 0; nf < 4; ++nf) {
        const int q = nf*16 + c;
        float M = fmaxf(fmaxf(MwS[0][q], MwS[1][q]), fmaxf(MwS[2][q], MwS[3][q]));
        float L = LwS[0][q]*__expf(MwS[0][q]-M) + LwS[1][q]*__expf(MwS[1][q]-M)
                + LwS[2][q]*__expf(MwS[2][q]-M) + LwS[3][q]*__expf(MwS[3][q]-M);
        fac[nf] = __expf(mst[nf] - M) / L;
    }
    #pragma unroll
    for (int mo = 0; mo < 4; ++mo)
        #pragma unroll
        for (int nf = 0; nf < 4; ++nf)
            #pragma unroll
            for (int r = 0; r < 4; ++r)
                atomicAdd(&Os[mo*16 + g*4 + r][nf*16 + c], acc[mo][nf][r] * fac[nf]);
    __syncthreads();

    // ---- transpose-write msgb[q][h*64+dh] bf16
    const int q = tid >> 2, dh0 = (tid & 3) * 16;
    unsigned int ov[8];
    #pragma unroll
    for (int i = 0; i < 8; ++i)
        ov[i] = (unsigned)f2bf(Os[dh0 + 2*i][q]) | ((unsigned)f2bf(Os[dh0 + 2*i + 1][q]) << 16);
    unsigned short* op = &msgb[(rowOff + qBase + q)*DD + hh*DHH + dh0];
    *(uint4*)&op[0] = *(uint4*)&ov[0];
    *(uint4*)&op[8] = *(uint4*)&ov[4];
}

// ------------------------------------------------- residual + LayerNorm (+delta, +bf16 copy)
template<int WITH_DELTA, int WBF16>
__global__ __launch_bounds__(256) void ln_kernel(
    const float* __restrict__ x, const float* __restrict__ y,
    const float* __restrict__ g, const float* __restrict__ bvec,
    float* __restrict__ out, unsigned short* __restrict__ outb,
    const float* __restrict__ href, float* __restrict__ deltaAcc)
{
    const int row = blockIdx.x;
    const int tid = threadIdx.x;
    const size_t base = (size_t)row * DD + tid*2;
    float2 xv = *(const float2*)(x + base);
    float2 yv = *(const float2*)(y + base);
    float v0 = xv.x + yv.x;
    float v1 = xv.y + yv.y;
    float s  = v0 + v1;
    float sq = v0*v0 + v1*v1;
    #pragma unroll
    for (int m = 1; m < 64; m <<= 1) {
        s  += __shfl_xor(s,  m, 64);
        sq += __shfl_xor(sq, m, 64);
    }
    __shared__ float redS[4], redQ[4];
    int wv = tid >> 6;
    if ((tid & 63) == 0) { redS[wv] = s; redQ[wv] = sq; }
    __syncthreads();
    s  = redS[0] + redS[1] + redS[2] + redS[3];
    sq = redQ[0] + redQ[1] + redQ[2] + redQ[3];
    float mu  = s * (1.f/DD);
    float var = sq * (1.f/DD) - mu*mu;
    float inv = rsqrtf(var + LN_EPS);
    float o0 = (v0 - mu)*inv*g[tid*2  ] + bvec[tid*2  ];
    float o1 = (v1 - mu)*inv*g[tid*2+1] + bvec[tid*2+1];
    float2 ov; ov.x = o0; ov.y = o1;
    *(float2*)(out + base) = ov;
    if (WBF16)
        ((unsigned int*)outb)[(size_t)row*(DD/2) + tid] =
            (unsigned)f2bf(o0) | ((unsigned)f2bf(o1) << 16);

    if (WITH_DELTA) {
        float d0 = o0 - href[base], d1 = o1 - href[base + 1];
        float ds = d0*d0 + d1*d1;
        #pragma unroll
        for (int m = 1; m < 64; m <<= 1) ds += __shfl_xor(ds, m, 64);
        __shared__ float redD[4];
        if ((tid & 63) == 0) redD[wv] = ds;
        __syncthreads();
        if (tid == 0) {
            float t = redD[0] + redD[1] + redD[2] + redD[3];
            atomicAdd(deltaAcc, sqrtf(t));
        }
    }
}

__global__ void delta_finalize(const float* __restrict__ acc, float* __restrict__ out)
{
    out[0] = acc[0] * (1.f / (float)MROWS);
}

// ---------------------------------------------------------------- launch
extern "C" void kernel_launch(void* const* d_in, const int* in_sizes, int n_in,
                              void* d_out, int out_size, void* d_ws, size_t ws_size,
                              hipStream_t stream)
{
    (void)in_sizes; (void)n_in; (void)out_size; (void)ws_size;
    const float* h      = (const float*)d_in[0];
    const float* phases = (const float*)d_in[1];
    const unsigned char* mask = (const unsigned char*)d_in[2];
    const float* Wq  = (const float*)d_in[3];
    const float* Wk  = (const float*)d_in[4];
    const float* Wp  = (const float*)d_in[5];
    const float* bp  = (const float*)d_in[6];
    const float* Wv  = (const float*)d_in[7];
    const float* Wo  = (const float*)d_in[8];
    const float* W1  = (const float*)d_in[9];
    const float* b1  = (const float*)d_in[10];
    const float* W2  = (const float*)d_in[11];
    const float* b2  = (const float*)d_in[12];
    const float* g1  = (const float*)d_in[13];
    const float* be1 = (const float*)d_in[14];
    const float* g2  = (const float*)d_in[15];
    const float* be2 = (const float*)d_in[16];
    const float* Wph = (const float*)d_in[17];
    const float* bph = (const float*)d_in[18];

    char* ws = (char*)d_ws;
    const size_t MB = 1024*1024;
    unsigned short* hb   = (unsigned short*)(ws);              // 4 MB
    unsigned short* WqT  = (unsigned short*)(ws + 4*MB);       // .5
    unsigned short* WkT  = (unsigned short*)(ws + 4*MB + 512*1024);
    unsigned short* WvT  = (unsigned short*)(ws + 5*MB);
    unsigned short* WoT  = (unsigned short*)(ws + 5*MB + 512*1024);
    unsigned short* W1T  = (unsigned short*)(ws + 6*MB);       // 2 MB
    unsigned short* W2T  = (unsigned short*)(ws + 8*MB);       // 2 MB
    unsigned short* Qb   = (unsigned short*)(ws + 10*MB);      // 4 MB (T1b aliases from here)
    unsigned short* Kb   = (unsigned short*)(ws + 14*MB);      // 4 MB
    unsigned short* Vb   = (unsigned short*)(ws + 18*MB);      // 4 MB
    unsigned short* VT   = (unsigned short*)(ws + 22*MB);      // 4 MB
    unsigned short* T1b  = Qb;                                 // 16 MB alias (Qb/Kb/Vb/VT dead)
    unsigned short* msgb = (unsigned short*)(ws + 26*MB);      // 4 MB
    float* mo    = (float*)(ws + 30*MB);                       // 8 MB (ffn aliases: mo dead after ln1)
    float* ffn   = mo;
    float* h1    = (float*)(ws + 38*MB);                       // 8 MB
    unsigned short* h1b = (unsigned short*)(ws + 46*MB);       // 4 MB
    float* cosPt = (float*)(ws + 50*MB);                       // 64 KB
    float* sinPt = (float*)(ws + 50*MB + 64*1024);             // 64 KB
    float* dAcc  = (float*)(ws + 50*MB + 128*1024);

    float* out_h2    = (float*)d_out;
    float* out_ph    = out_h2 + (size_t)MROWS*DD;
    float* out_delta = out_ph + MROWS*HH;

    hipMemsetAsync(dAcc, 0, sizeof(float), stream);

    dim3 blk(256);
    // bf16 conversion of h
    convert_bf16_kernel<<<dim3(MROWS*DD/8/256), blk, 0, stream>>>(h, hb, MROWS*DD/8);
    // weight transposes (f32[K][N] -> bf16[N][K])
    wtrans_kernel<<<dim3(DD/32, DD/32), blk, 0, stream>>>(Wq, WqT, DD, DD);
    wtrans_kernel<<<dim3(DD/32, DD/32), blk, 0, stream>>>(Wk, WkT, DD, DD);
    wtrans_kernel<<<dim3(DD/32, DD/32), blk, 0, stream>>>(Wv, WvT, DD, DD);
    wtrans_kernel<<<dim3(DD/32, DD/32), blk, 0, stream>>>(Wo, WoT, DD, DD);
    wtrans_kernel<<<dim3(FF/32, DD/32), blk, 0, stream>>>(W1, W1T, DD, FF);
    wtrans_kernel<<<dim3(DD/32, FF/32), blk, 0, stream>>>(W2, W2T, FF, DD);
    // phases
    phase_proj_kernel<<<dim3(MROWS/32), blk, 0, stream>>>(h, Wp, bp, cosPt, sinPt);
    // QKV projections
    mfma_gemm<1,0,0><<<dim3(DD/128, MROWS/128), blk, 0, stream>>>(hb, WqT, nullptr, Qb, MROWS, DD, DD);
    mfma_gemm<1,0,0><<<dim3(DD/128, MROWS/128), blk, 0, stream>>>(hb, WkT, nullptr, Kb, MROWS, DD, DD);
    mfma_gemm<1,0,0><<<dim3(DD/128, MROWS/128), blk, 0, stream>>>(hb, WvT, nullptr, Vb, MROWS, DD, DD);
    vtrans_kernel<<<dim3(NN/32, DD/32, BB), blk, 0, stream>>>(Vb, VT);
    // attention
    attn_kernel<<<dim3(NN/64, HH, BB), blk, 0, stream>>>(Qb, Kb, VT, cosPt, sinPt, mask, msgb);
    // output projection + LN1
    mfma_gemm<0,0,0><<<dim3(DD/128, MROWS/128), blk, 0, stream>>>(msgb, WoT, nullptr, mo, MROWS, DD, DD);
    ln_kernel<0,1><<<dim3(MROWS), blk, 0, stream>>>(h, mo, g1, be1, h1, h1b, nullptr, nullptr);
    // FFN
    mfma_gemm<1,1,1><<<dim3(FF/128, MROWS/128), blk, 0, stream>>>(h1b, W1T, b1, T1b, MROWS, FF, DD);
    mfma_gemm<0,1,0><<<dim3(DD/128, MROWS/128), blk, 0, stream>>>(T1b, W2T, b2, ffn, MROWS, DD, FF);
    ln_kernel<1,0><<<dim3(MROWS), blk, 0, stream>>>(h1, ffn, g2, be2, out_h2, nullptr, h, dAcc);
    // phase update + delta
    phase_update_kernel<<<dim3(MROWS/32), blk, 0, stream>>>(out_h2, Wph, bph, phases, out_ph);
    delta_finalize<<<dim3(1), dim3(1), 0, stream>>>(dAcc, out_delta);
}

// Round 6
// 511.464 us; speedup vs baseline: 1.6781x; 1.2013x over previous
//
#include <hip/hip_runtime.h>
#include <math.h>

#define BB 2
#define NN 2048
#define DD 512
#define HH 8
#define DHH 64
#define FF 2048
#define MROWS (BB*NN)   // 4096
#define LN_EPS 1e-5f
#define PHASE_ALPHA 0.1f
#define PI_F 3.14159265358979323846f
#define SCALE 0.125f    // 1/sqrt(64)
#define QLD (3*DD)      // fused QKV row stride

typedef __attribute__((ext_vector_type(8))) short  bf16x8;
typedef __attribute__((ext_vector_type(4))) float  f32x4;
typedef __attribute__((ext_vector_type(4))) unsigned short us4;

__device__ __forceinline__ unsigned short f2bf(float x) {
    unsigned int u = __float_as_uint(x);
    u += 0x7fffu + ((u >> 16) & 1u);      // RNE
    return (unsigned short)(u >> 16);
}

// ---------------------------------------------------------------- bf16 convert
__global__ __launch_bounds__(256) void convert_bf16_kernel(
    const float* __restrict__ X, unsigned short* __restrict__ Y, int n8)
{
    int i = blockIdx.x*256 + threadIdx.x;
    if (i >= n8) return;
    const float4 a = *(const float4*)&X[i*8];
    const float4 b = *(const float4*)&X[i*8 + 4];
    uint4 o;
    o.x = (unsigned)f2bf(a.x) | ((unsigned)f2bf(a.y) << 16);
    o.y = (unsigned)f2bf(a.z) | ((unsigned)f2bf(a.w) << 16);
    o.z = (unsigned)f2bf(b.x) | ((unsigned)f2bf(b.y) << 16);
    o.w = (unsigned)f2bf(b.z) | ((unsigned)f2bf(b.w) << 16);
    *(uint4*)&Y[i*8] = o;
}

// ------------------------------------------- weight transpose f32[K][N] -> bf16[N][K]
__global__ __launch_bounds__(256) void wtrans_kernel(
    const float* __restrict__ W, unsigned short* __restrict__ WT, int K, int N)
{
    __shared__ unsigned short T[32][33];
    const int k0 = blockIdx.y*32, n0 = blockIdx.x*32;
    const int r = threadIdx.x >> 3, cc = (threadIdx.x & 7)*4;
    float4 v = *(const float4*)&W[(size_t)(k0 + r)*N + n0 + cc];
    T[cc+0][r] = f2bf(v.x); T[cc+1][r] = f2bf(v.y);
    T[cc+2][r] = f2bf(v.z); T[cc+3][r] = f2bf(v.w);
    __syncthreads();
    us4 o; o.x = T[r][cc]; o.y = T[r][cc+1]; o.z = T[r][cc+2]; o.w = T[r][cc+3];
    *(us4*)&WT[(size_t)(n0 + r)*K + k0 + cc] = o;
}

// ------------------------------------------- V transpose (fused QKV col 1024+) -> VT[(b,h,dh)][N]
__global__ __launch_bounds__(256) void vtrans_kernel(
    const unsigned short* __restrict__ qkv, unsigned short* __restrict__ VT)
{
    __shared__ unsigned short T[32][33];
    const int b = blockIdx.z;
    const int n0 = blockIdx.x*32, c0 = blockIdx.y*32;
    const int r = threadIdx.x >> 3, cc = (threadIdx.x & 7)*4;
    us4 v = *(const us4*)&qkv[((size_t)b*NN + n0 + r)*QLD + 2*DD + c0 + cc];
    T[cc+0][r] = v.x; T[cc+1][r] = v.y; T[cc+2][r] = v.z; T[cc+3][r] = v.w;
    __syncthreads();
    const int cg = c0 + r;                 // global col = h*64+dh
    const int hh = cg >> 6, dh = cg & 63;
    us4 o; o.x = T[r][cc]; o.y = T[r][cc+1]; o.z = T[r][cc+2]; o.w = T[r][cc+3];
    *(us4*)&VT[(((size_t)b*HH + hh)*DHH + dh)*NN + n0 + cc] = o;
}

// ---------------------------------------------------------------- MFMA GEMM
// C[M,Nc] = A[M,K] @ BT[Nc,K]^T, bf16 row-major K-contiguous, BK=64.
// 256 threads = 4 waves (2x2); wave tile (BM/2)x(BN/2); frags FM=BM/32, FN=BN/32.
// SPLITK>1: blockIdx.z selects K-chunk; ATOMIC=1 does f32 atomicAdd epilogue.
template<int BM, int BN, int SPLITK, int OUTBF16, int BIAS, int ACT, int ATOMIC>
__global__ __launch_bounds__(256, 2) void mfma_gemm(
    const unsigned short* __restrict__ A, const unsigned short* __restrict__ BT,
    const float* __restrict__ bias, void* __restrict__ Cout,
    int M, int Nc, int K)
{
    constexpr int FM = BM/32, FN = BN/32;
    constexpr int ROWS = BM + BN;
    constexpr int NLOAD = ROWS*8/256;
    __shared__ unsigned short Ss[ROWS][72];   // A rows [0,BM), B rows [BM,BM+BN)

    const int tid = threadIdx.x;
    const int w = tid >> 6, lane = tid & 63;
    const int c = lane & 15, g = lane >> 4;
    const int wr = w >> 1, wc = w & 1;
    const int bm = blockIdx.y*BM, bn = blockIdx.x*BN;
    const int k0 = (SPLITK > 1) ? blockIdx.z * (K / SPLITK) : 0;
    const int NT = (K / SPLITK) / 64;

    f32x4 zero = {0.f, 0.f, 0.f, 0.f};
    f32x4 acc[FM][FN];
    #pragma unroll
    for (int i = 0; i < FM; ++i)
        #pragma unroll
        for (int j = 0; j < FN; ++j) acc[i][j] = zero;

    uint4 pf[NLOAD];
    #pragma unroll
    for (int l = 0; l < NLOAD; ++l) {
        const int i = tid + l*256;
        const int r = i >> 3, kc = (i & 7)*8;
        const unsigned short* src = (r < BM) ? &A [(size_t)(bm + r)*K + k0 + kc]
                                             : &BT[(size_t)(bn + r - BM)*K + k0 + kc];
        pf[l] = *(const uint4*)src;
    }

    for (int kt = 0; kt < NT; ++kt) {
        __syncthreads();
        #pragma unroll
        for (int l = 0; l < NLOAD; ++l) {
            const int i = tid + l*256;
            *(uint4*)&Ss[i >> 3][(i & 7)*8] = pf[l];
        }
        __syncthreads();
        if (kt + 1 < NT) {
            #pragma unroll
            for (int l = 0; l < NLOAD; ++l) {
                const int i = tid + l*256;
                const int r = i >> 3, kc = (i & 7)*8;
                const unsigned short* src = (r < BM)
                    ? &A [(size_t)(bm + r)*K + k0 + (kt+1)*64 + kc]
                    : &BT[(size_t)(bn + r - BM)*K + k0 + (kt+1)*64 + kc];
                pf[l] = *(const uint4*)src;
            }
        }
        #pragma unroll
        for (int ks = 0; ks < 2; ++ks) {
            bf16x8 af[FM], bfr[FN];
            #pragma unroll
            for (int mf = 0; mf < FM; ++mf)
                af[mf] = *(const bf16x8*)&Ss[wr*(BM/2) + mf*16 + c][ks*32 + g*8];
            #pragma unroll
            for (int nf = 0; nf < FN; ++nf)
                bfr[nf] = *(const bf16x8*)&Ss[BM + wc*(BN/2) + nf*16 + c][ks*32 + g*8];
            #pragma unroll
            for (int mf = 0; mf < FM; ++mf)
                #pragma unroll
                for (int nf = 0; nf < FN; ++nf)
                    acc[mf][nf] = __builtin_amdgcn_mfma_f32_16x16x32_bf16(
                        af[mf], bfr[nf], acc[mf][nf], 0, 0, 0);
        }
    }

    #pragma unroll
    for (int mf = 0; mf < FM; ++mf)
        #pragma unroll
        for (int nf = 0; nf < FN; ++nf) {
            const int col = bn + wc*(BN/2) + nf*16 + c;
            const float bv = BIAS ? bias[col] : 0.f;
            #pragma unroll
            for (int r = 0; r < 4; ++r) {
                const int row = bm + wr*(BM/2) + mf*16 + g*4 + r;
                float x = acc[mf][nf][r] + bv;
                if (ACT == 1) x = 0.5f * x * (1.f + erff(x * 0.70710678118654752f));
                if (ATOMIC)       atomicAdd(&((float*)Cout)[(size_t)row*Nc + col], x);
                else if (OUTBF16) ((unsigned short*)Cout)[(size_t)row*Nc + col] = f2bf(x);
                else              ((float*)Cout)[(size_t)row*Nc + col] = x;
            }
        }
}

// ------------------------------------------------- phase projection + cos/sin (-> [b,h][n])
__global__ __launch_bounds__(256) void phase_proj_kernel(
    const float* __restrict__ X, const float* __restrict__ Wp,
    const float* __restrict__ bp, float* __restrict__ cosPt, float* __restrict__ sinPt)
{
    __shared__ float Wl[DD*HH];
    for (int i = threadIdx.x; i < DD*HH; i += 256) Wl[i] = Wp[i];
    __syncthreads();
    int row = blockIdx.x*32 + (threadIdx.x >> 3);
    int hh  = threadIdx.x & 7;
    const float* xr = X + (size_t)row * DD;
    float acc = bp[hh];
    for (int k = 0; k < DD; k += 4) {
        float4 xv = *(const float4*)&xr[k];
        acc += xv.x*Wl[(k  )*HH+hh] + xv.y*Wl[(k+1)*HH+hh]
             + xv.z*Wl[(k+2)*HH+hh] + xv.w*Wl[(k+3)*HH+hh];
    }
    const int b = row >> 11, n = row & (NN-1);
    cosPt[((size_t)b*HH + hh)*NN + n] = cosf(acc);
    sinPt[((size_t)b*HH + hh)*NN + n] = sinf(acc);
}

// ------------------------------------------------- final phase update
__global__ __launch_bounds__(256) void phase_update_kernel(
    const float* __restrict__ H2, const float* __restrict__ Wph,
    const float* __restrict__ bph, const float* __restrict__ phases,
    float* __restrict__ phases_out)
{
    __shared__ float Wl[DD*HH];
    for (int i = threadIdx.x; i < DD*HH; i += 256) Wl[i] = Wph[i];
    __syncthreads();
    int row = blockIdx.x*32 + (threadIdx.x >> 3);
    int hh  = threadIdx.x & 7;
    const float* xr = H2 + (size_t)row * DD;
    float acc = bph[hh];
    for (int k = 0; k < DD; k += 4) {
        float4 xv = *(const float4*)&xr[k];
        acc += xv.x*Wl[(k  )*HH+hh] + xv.y*Wl[(k+1)*HH+hh]
             + xv.z*Wl[(k+2)*HH+hh] + xv.w*Wl[(k+3)*HH+hh];
    }
    phases_out[row*HH + hh] = phases[row*HH + hh] + PHASE_ALPHA * tanhf(acc) * PI_F;
}

// ------------------------------------------------- MFMA flash attention w/ harmonic
// Q/K read from fused QKV buffer (stride QLD, K at col DD). 4 waves; wave w owns
// 32-key subtiles s%4==w, independent online softmax, merged at end.
__global__ __launch_bounds__(256, 2) void attn_kernel(
    const unsigned short* __restrict__ qkv, const unsigned short* __restrict__ VT,
    const float* __restrict__ cosPt, const float* __restrict__ sinPt,
    const unsigned char* __restrict__ mask, unsigned short* __restrict__ msgb)
{
    __shared__ float Os[64][68];          // O^T accum [dh][q]
    __shared__ float MwS[4][64], LwS[4][64];
    __shared__ unsigned short Pl[4][64][40];   // per-wave P [q][key_rel], 80B rows

    const int tid = threadIdx.x;
    const int w = tid >> 6, lane = tid & 63;
    const int c = lane & 15, g = lane >> 4;
    const int qBase = blockIdx.x * 64;
    const int hh = blockIdx.y, b = blockIdx.z;
    const size_t rowOff = (size_t)b * NN;
    const int bh = b*HH + hh;
    const size_t cosBase = (size_t)bh * NN;

    for (int i = tid; i < 64*68; i += 256) ((float*)Os)[i] = 0.f;

    // Q B-frags (held in registers for the whole block)
    bf16x8 qf[4][2];
    #pragma unroll
    for (int nf = 0; nf < 4; ++nf)
        #pragma unroll
        for (int ks = 0; ks < 2; ++ks)
            qf[nf][ks] = *(const bf16x8*)&qkv[(rowOff + qBase + nf*16 + c)*QLD
                                              + hh*DHH + ks*32 + g*8];
    float cq[4], sq[4];
    #pragma unroll
    for (int nf = 0; nf < 4; ++nf) {
        cq[nf] = cosPt[cosBase + qBase + nf*16 + c];
        sq[nf] = sinPt[cosBase + qBase + nf*16 + c];
    }

    f32x4 zero = {0.f, 0.f, 0.f, 0.f};
    f32x4 acc[4][4];
    #pragma unroll
    for (int i = 0; i < 4; ++i)
        #pragma unroll
        for (int j = 0; j < 4; ++j) acc[i][j] = zero;
    float mst[4], lst[4];
    #pragma unroll
    for (int i = 0; i < 4; ++i) { mst[i] = -INFINITY; lst[i] = 0.f; }

    __syncthreads();   // Os zeroed

    for (int s = w; s < NN/32; s += 4) {
        const int kb0 = s * 32;
        // ---- S^T = K·Q^T (32 keys x 64 q)
        f32x4 st[2][4];
        #pragma unroll
        for (int mf = 0; mf < 2; ++mf) {
            bf16x8 kf0 = *(const bf16x8*)&qkv[(rowOff + kb0 + mf*16 + c)*QLD + DD + hh*DHH + g*8];
            bf16x8 kf1 = *(const bf16x8*)&qkv[(rowOff + kb0 + mf*16 + c)*QLD + DD + hh*DHH + 32 + g*8];
            #pragma unroll
            for (int nf = 0; nf < 4; ++nf) {
                st[mf][nf] = __builtin_amdgcn_mfma_f32_16x16x32_bf16(kf0, qf[nf][0], zero, 0, 0, 0);
                st[mf][nf] = __builtin_amdgcn_mfma_f32_16x16x32_bf16(kf1, qf[nf][1], st[mf][nf], 0, 0, 0);
            }
        }
        // ---- harmonic * scale, mask
        #pragma unroll
        for (int mf = 0; mf < 2; ++mf) {
            const int keyb = kb0 + mf*16 + g*4;
            const f32x4 ck = *(const f32x4*)&cosPt[cosBase + keyb];
            const f32x4 sk = *(const f32x4*)&sinPt[cosBase + keyb];
            const unsigned int mk = *(const unsigned int*)&mask[rowOff + keyb];
            #pragma unroll
            for (int nf = 0; nf < 4; ++nf)
                #pragma unroll
                for (int r = 0; r < 4; ++r) {
                    float wgt = 0.5f + 0.5f*(cq[nf]*ck[r] + sq[nf]*sk[r]);
                    float v = st[mf][nf][r] * SCALE * wgt;
                    st[mf][nf][r] = ((mk >> (8*r)) & 0xff) ? -INFINITY : v;
                }
        }
        // ---- online softmax per q-column (keys: in-lane mf,r + lanes g)
        #pragma unroll
        for (int nf = 0; nf < 4; ++nf) {
            float tmax = -INFINITY;
            #pragma unroll
            for (int mf = 0; mf < 2; ++mf)
                #pragma unroll
                for (int r = 0; r < 4; ++r) tmax = fmaxf(tmax, st[mf][nf][r]);
            tmax = fmaxf(tmax, __shfl_xor(tmax, 16));
            tmax = fmaxf(tmax, __shfl_xor(tmax, 32));
            const float mnew = fmaxf(mst[nf], tmax);
            const float corr = (mst[nf] == -INFINITY) ? 0.f : __expf(mst[nf] - mnew);
            float psum = 0.f;
            unsigned short* prow = &Pl[w][nf*16 + c][0];
            #pragma unroll
            for (int mf = 0; mf < 2; ++mf) {
                float p0 = __expf(st[mf][nf][0] - mnew);
                float p1 = __expf(st[mf][nf][1] - mnew);
                float p2 = __expf(st[mf][nf][2] - mnew);
                float p3 = __expf(st[mf][nf][3] - mnew);
                psum += (p0 + p1) + (p2 + p3);
                *(unsigned int*)&prow[mf*16 + g*4    ] = (unsigned)f2bf(p0) | ((unsigned)f2bf(p1) << 16);
                *(unsigned int*)&prow[mf*16 + g*4 + 2] = (unsigned)f2bf(p2) | ((unsigned)f2bf(p3) << 16);
            }
            psum += __shfl_xor(psum, 16);
            psum += __shfl_xor(psum, 32);
            lst[nf] = lst[nf]*corr + psum;
            mst[nf] = mnew;
            #pragma unroll
            for (int mo = 0; mo < 4; ++mo)
                #pragma unroll
                for (int r = 0; r < 4; ++r) acc[mo][nf][r] *= corr;
        }
        // ---- O^T += V^T · P^T  (wave-private, no barrier needed)
        bf16x8 vf[4], pfr[4];
        #pragma unroll
        for (int mo = 0; mo < 4; ++mo)
            vf[mo] = *(const bf16x8*)&VT[((size_t)bh*DHH + mo*16 + c)*NN + kb0 + g*8];
        #pragma unroll
        for (int nf = 0; nf < 4; ++nf)
            pfr[nf] = *(const bf16x8*)&Pl[w][nf*16 + c][g*8];
        #pragma unroll
        for (int mo = 0; mo < 4; ++mo)
            #pragma unroll
            for (int nf = 0; nf < 4; ++nf)
                acc[mo][nf] = __builtin_amdgcn_mfma_f32_16x16x32_bf16(
                    vf[mo], pfr[nf], acc[mo][nf], 0, 0, 0);
    }

    // ---- merge the 4 wave-partials
    if (lane < 16) {
        #pragma unroll
        for (int nf = 0; nf < 4; ++nf) {
            MwS[w][nf*16 + lane] = mst[nf];
            LwS[w][nf*16 + lane] = lst[nf];
        }
    }
    __syncthreads();
    float fac[4];
    #pragma unroll
    for (int nf = 0; nf < 4; ++nf) {
        const int q = nf*16 + c;
        float M = fmaxf(fmaxf(MwS[0][q], MwS[1][q]), fmaxf(MwS[2][q], MwS[3][q]));
        float L = LwS[0][q]*__expf(MwS[0][q]-M) + LwS[1][q]*__expf(MwS[1][q]-M)
                + LwS[2][q]*__expf(MwS[2][q]-M) + LwS[3][q]*__expf(MwS[3][q]-M);
        fac[nf] = __expf(mst[nf] - M) / L;
    }
    #pragma unroll
    for (int mo = 0; mo < 4; ++mo)
        #pragma unroll
        for (int nf = 0; nf < 4; ++nf)
            #pragma unroll
            for (int r = 0; r < 4; ++r)
                atomicAdd(&Os[mo*16 + g*4 + r][nf*16 + c], acc[mo][nf][r] * fac[nf]);
    __syncthreads();

    // ---- transpose-write msgb[q][h*64+dh] bf16
    const int q = tid >> 2, dh0 = (tid & 3) * 16;
    unsigned int ov[8];
    #pragma unroll
    for (int i = 0; i < 8; ++i)
        ov[i] = (unsigned)f2bf(Os[dh0 + 2*i][q]) | ((unsigned)f2bf(Os[dh0 + 2*i + 1][q]) << 16);
    unsigned short* op = &msgb[(rowOff + qBase + q)*DD + hh*DHH + dh0];
    *(uint4*)&op[0] = *(uint4*)&ov[0];
    *(uint4*)&op[8] = *(uint4*)&ov[4];
}

// ------------------------------------------------- residual + LayerNorm (+delta, +bf16 copy, +ybias)
template<int WITH_DELTA, int WBF16, int YBIAS>
__global__ __launch_bounds__(256) void ln_kernel(
    const float* __restrict__ x, const float* __restrict__ y,
    const float* __restrict__ g, const float* __restrict__ bvec,
    const float* __restrict__ ybias,
    float* __restrict__ out, unsigned short* __restrict__ outb,
    const float* __restrict__ href, float* __restrict__ deltaAcc)
{
    const int row = blockIdx.x;
    const int tid = threadIdx.x;
    const size_t base = (size_t)row * DD + tid*2;
    float2 xv = *(const float2*)(x + base);
    float2 yv = *(const float2*)(y + base);
    float v0 = xv.x + yv.x;
    float v1 = xv.y + yv.y;
    if (YBIAS) { v0 += ybias[tid*2]; v1 += ybias[tid*2+1]; }
    float s  = v0 + v1;
    float sq = v0*v0 + v1*v1;
    #pragma unroll
    for (int m = 1; m < 64; m <<= 1) {
        s  += __shfl_xor(s,  m, 64);
        sq += __shfl_xor(sq, m, 64);
    }
    __shared__ float redS[4], redQ[4];
    int wv = tid >> 6;
    if ((tid & 63) == 0) { redS[wv] = s; redQ[wv] = sq; }
    __syncthreads();
    s  = redS[0] + redS[1] + redS[2] + redS[3];
    sq = redQ[0] + redQ[1] + redQ[2] + redQ[3];
    float mu  = s * (1.f/DD);
    float var = sq * (1.f/DD) - mu*mu;
    float inv = rsqrtf(var + LN_EPS);
    float o0 = (v0 - mu)*inv*g[tid*2  ] + bvec[tid*2  ];
    float o1 = (v1 - mu)*inv*g[tid*2+1] + bvec[tid*2+1];
    float2 ov; ov.x = o0; ov.y = o1;
    *(float2*)(out + base) = ov;
    if (WBF16)
        ((unsigned int*)outb)[(size_t)row*(DD/2) + tid] =
            (unsigned)f2bf(o0) | ((unsigned)f2bf(o1) << 16);

    if (WITH_DELTA) {
        float d0 = o0 - href[base], d1 = o1 - href[base + 1];
        float ds = d0*d0 + d1*d1;
        #pragma unroll
        for (int m = 1; m < 64; m <<= 1) ds += __shfl_xor(ds, m, 64);
        __shared__ float redD[4];
        if ((tid & 63) == 0) redD[wv] = ds;
        __syncthreads();
        if (tid == 0) {
            float t = redD[0] + redD[1] + redD[2] + redD[3];
            atomicAdd(deltaAcc, sqrtf(t));
        }
    }
}

__global__ void delta_finalize(const float* __restrict__ acc, float* __restrict__ out)
{
    out[0] = acc[0] * (1.f / (float)MROWS);
}

// ---------------------------------------------------------------- launch
extern "C" void kernel_launch(void* const* d_in, const int* in_sizes, int n_in,
                              void* d_out, int out_size, void* d_ws, size_t ws_size,
                              hipStream_t stream)
{
    (void)in_sizes; (void)n_in; (void)out_size; (void)ws_size;
    const float* h      = (const float*)d_in[0];
    const float* phases = (const float*)d_in[1];
    const unsigned char* mask = (const unsigned char*)d_in[2];
    const float* Wq  = (const float*)d_in[3];
    const float* Wk  = (const float*)d_in[4];
    const float* Wp  = (const float*)d_in[5];
    const float* bp  = (const float*)d_in[6];
    const float* Wv  = (const float*)d_in[7];
    const float* Wo  = (const float*)d_in[8];
    const float* W1  = (const float*)d_in[9];
    const float* b1  = (const float*)d_in[10];
    const float* W2  = (const float*)d_in[11];
    const float* b2  = (const float*)d_in[12];
    const float* g1  = (const float*)d_in[13];
    const float* be1 = (const float*)d_in[14];
    const float* g2  = (const float*)d_in[15];
    const float* be2 = (const float*)d_in[16];
    const float* Wph = (const float*)d_in[17];
    const float* bph = (const float*)d_in[18];

    char* ws = (char*)d_ws;
    const size_t MB = 1024*1024;
    unsigned short* hb   = (unsigned short*)(ws);              // 4 MB
    unsigned short* WqT  = (unsigned short*)(ws + 4*MB);       // .5  (Wq/Wk/Wv contiguous = fused BT)
    unsigned short* WkT  = (unsigned short*)(ws + 4*MB + 512*1024);
    unsigned short* WvT  = (unsigned short*)(ws + 5*MB);
    unsigned short* WoT  = (unsigned short*)(ws + 5*MB + 512*1024);
    unsigned short* W1T  = (unsigned short*)(ws + 6*MB);       // 2 MB
    unsigned short* W2T  = (unsigned short*)(ws + 8*MB);       // 2 MB
    unsigned short* qkvb = (unsigned short*)(ws + 10*MB);      // 12 MB [4096][1536]
    unsigned short* VT   = (unsigned short*)(ws + 22*MB);      // 4 MB
    unsigned short* T1b  = qkvb;                               // 16 MB alias (qkv/VT dead after attn)
    unsigned short* msgb = (unsigned short*)(ws + 26*MB);      // 4 MB
    float* mo    = (float*)(ws + 30*MB);                       // 8 MB (ffn aliases: mo dead after ln1)
    float* ffn   = mo;
    float* h1    = (float*)(ws + 38*MB);                       // 8 MB
    unsigned short* h1b = (unsigned short*)(ws + 46*MB);       // 4 MB
    float* cosPt = (float*)(ws + 50*MB);                       // 64 KB
    float* sinPt = (float*)(ws + 50*MB + 64*1024);             // 64 KB
    float* dAcc  = (float*)(ws + 50*MB + 128*1024);

    float* out_h2    = (float*)d_out;
    float* out_ph    = out_h2 + (size_t)MROWS*DD;
    float* out_delta = out_ph + MROWS*HH;

    hipMemsetAsync(dAcc, 0, sizeof(float), stream);

    dim3 blk(256);
    // bf16 conversion of h
    convert_bf16_kernel<<<dim3(MROWS*DD/8/256), blk, 0, stream>>>(h, hb, MROWS*DD/8);
    // weight transposes (f32[K][N] -> bf16[N][K])
    wtrans_kernel<<<dim3(DD/32, DD/32), blk, 0, stream>>>(Wq, WqT, DD, DD);
    wtrans_kernel<<<dim3(DD/32, DD/32), blk, 0, stream>>>(Wk, WkT, DD, DD);
    wtrans_kernel<<<dim3(DD/32, DD/32), blk, 0, stream>>>(Wv, WvT, DD, DD);
    wtrans_kernel<<<dim3(DD/32, DD/32), blk, 0, stream>>>(Wo, WoT, DD, DD);
    wtrans_kernel<<<dim3(FF/32, DD/32), blk, 0, stream>>>(W1, W1T, DD, FF);
    wtrans_kernel<<<dim3(DD/32, FF/32), blk, 0, stream>>>(W2, W2T, FF, DD);
    // phases
    phase_proj_kernel<<<dim3(MROWS/32), blk, 0, stream>>>(h, Wp, bp, cosPt, sinPt);
    // fused QKV projection: Nc = 1536, tile 64x128 -> 768 blocks
    mfma_gemm<64,128,1,1,0,0,0><<<dim3((3*DD)/128, MROWS/64), blk, 0, stream>>>(
        hb, WqT, nullptr, qkvb, MROWS, 3*DD, DD);
    vtrans_kernel<<<dim3(NN/32, DD/32, BB), blk, 0, stream>>>(qkvb, VT);
    // attention
    attn_kernel<<<dim3(NN/64, HH, BB), blk, 0, stream>>>(qkvb, VT, cosPt, sinPt, mask, msgb);
    // output projection (64x64 tile -> 512 blocks) + LN1
    mfma_gemm<64,64,1,0,0,0,0><<<dim3(DD/64, MROWS/64), blk, 0, stream>>>(
        msgb, WoT, nullptr, mo, MROWS, DD, DD);
    ln_kernel<0,1,0><<<dim3(MROWS), blk, 0, stream>>>(h, mo, g1, be1, nullptr, h1, h1b, nullptr, nullptr);
    // FFN: W1 128x128 (512 blocks); W2 64x64 split-K=2 (1024 blocks, atomic f32)
    mfma_gemm<128,128,1,1,1,1,0><<<dim3(FF/128, MROWS/128), blk, 0, stream>>>(
        h1b, W1T, b1, T1b, MROWS, FF, DD);
    hipMemsetAsync(ffn, 0, (size_t)MROWS*DD*sizeof(float), stream);
    mfma_gemm<64,64,2,0,0,0,1><<<dim3(DD/64, MROWS/64, 2), blk, 0, stream>>>(
        T1b, W2T, nullptr, ffn, MROWS, DD, FF);
    ln_kernel<1,0,1><<<dim3(MROWS), blk, 0, stream>>>(h1, ffn, g2, be2, b2, out_h2, nullptr, h, dAcc);
    // phase update + delta
    phase_update_kernel<<<dim3(MROWS/32), blk, 0, stream>>>(out_h2, Wph, bph, phases, out_ph);
    delta_finalize<<<dim3(1), dim3(1), 0, stream>>>(dAcc, out_delta);
}